// Round 9
// baseline (153.756 us; speedup 1.0000x reference)
//
#include <hip/hip_runtime.h>

// CLUB loss, algebraically collapsed (O(N*d), x read once):
//   out = -0.5/N * P + 0.5/N^2 * ( <Sx2,Sinv> - 2<Sx,Smuinv> + N*Smu2inv )
// Sinv[d]=sum_i e^{-lv}, Smuinv[d]=sum_i mu e^{-lv}, Sx[d]=sum_j x, Sx2[d]=sum_j x^2
// P = sum (x-mu)^2 e^{-lv},  Smu2inv = sum mu^2 e^{-lv}
//
// R9: occupancy-driven MLP. Column-private barrier-free (R7) but 8-row chunks:
// 1568 blocks (~6 blocks/CU, ~24 waves/CU = 2x every prior round) and a
// moderate 18-load upfront batch (fits in ~45 VGPRs; R8's 36-load batch was
// VGPR-starved at 36 and serialized). Zero barriers before the tail.

#define Dd   512
#define HWs  784
#define Nn   6272
#define NBLK 1568     // 8 b * 2 col-halves * 98 row-chunks (8 rows each)
#define REP  64

// ws floats: Inv (0*REP+rep)*512+c | Mu (1*REP..) | Sx (2*REP..) | Sx2 (3*REP..)
// doubles @byte 524288: P[64], M2[64].  uint counter @byte 525312.

__global__ __launch_bounds__(256) void club_all(
    const float* __restrict__ x, const float* __restrict__ p_mu,
    const float* __restrict__ p_lv, float* __restrict__ ws,
    float* __restrict__ out)
{
    __shared__ float sbuf[16];
    __shared__ int lastFlag;
    __shared__ double redd[256];

    const int t     = threadIdx.x;
    const int blk   = blockIdx.x;
    const int b     = blk / 196;
    const int rem   = blk % 196;
    const int half  = rem & 1;
    const int chunk = rem >> 1;          // 0..97
    const int hw0   = chunk * 8;
    const int c     = 256 * half + t;    // this thread's column
    const int r0    = b * HWs + hw0;
    const int rep   = blk & (REP - 1);

    // ---- 18 independent loads upfront (2 dwordx4 + 16 dword) ----
    const float* xr = x + ((size_t)(b * Dd + c) * HWs + hw0);  // 32B-aligned
    const float4 xq0 = *(const float4*)(xr + 0);
    const float4 xq1 = *(const float4*)(xr + 4);

    const float* mp = p_mu + (size_t)r0 * Dd + c;
    const float* lp = p_lv + (size_t)r0 * Dd + c;
    float mu[8], lv[8];
#pragma unroll
    for (int j = 0; j < 8; ++j) mu[j] = mp[(size_t)j * Dd];
#pragma unroll
    for (int j = 0; j < 8; ++j) lv[j] = lp[(size_t)j * Dd];

    const float xv[8] = {xq0.x, xq0.y, xq0.z, xq0.w,
                         xq1.x, xq1.y, xq1.z, xq1.w};

    float sI = 0.f, sM = 0.f, sX = 0.f, sX2 = 0.f, aP = 0.f, aM2 = 0.f;
#pragma unroll
    for (int j = 0; j < 8; ++j) {
        const float iev = __expf(-lv[j]);
        const float dd  = xv[j] - mu[j];
        aP += dd * dd * iev;
        sI += iev;
        const float mi = mu[j] * iev;
        sM += mi; aM2 += mu[j] * mi;
        sX += xv[j]; sX2 += xv[j] * xv[j];
    }

    // ---- scalar P/M2: wave shuffle -> LDS -> one double atomic each ----
#pragma unroll
    for (int off = 32; off > 0; off >>= 1) {
        aP  += __shfl_down(aP,  off);
        aM2 += __shfl_down(aM2, off);
    }
    if ((t & 63) == 0) { sbuf[t >> 6] = aP; sbuf[8 + (t >> 6)] = aM2; }
    __syncthreads();     // only barrier before finalize

    // ---- fire-and-forget atomics: own column, 64-way replicas ----
    atomicAdd(&ws[(0 * REP + rep) * Dd + c], sI);
    atomicAdd(&ws[(1 * REP + rep) * Dd + c], sM);
    atomicAdd(&ws[(2 * REP + rep) * Dd + c], sX);
    atomicAdd(&ws[(3 * REP + rep) * Dd + c], sX2);
    if (t == 0) {
        double* wd = (double*)((char*)ws + 524288);
        atomicAdd(wd + rep,       (double)(sbuf[0] + sbuf[1] + sbuf[2] + sbuf[3]));
        atomicAdd(wd + REP + rep, (double)(sbuf[8] + sbuf[9] + sbuf[10] + sbuf[11]));
    }

    // ---- last-block-done finalize ----
    if (t == 0) {
        __threadfence();
        unsigned* ctr = (unsigned*)((char*)ws + 525312);
        lastFlag = (atomicAdd(ctr, 1u) == NBLK - 1);
    }
    __syncthreads();
    if (!lastFlag) return;

    __threadfence();
    double dc = 0.0;
#pragma unroll
    for (int hh = 0; hh < 2; ++hh) {
        const int cc = t + 256 * hh;
        double vI = 0.0, vM = 0.0, vX = 0.0, v2 = 0.0;
        for (int r = 0; r < REP; ++r) {
            vI += (double)__hip_atomic_load(ws + (0 * REP + r) * Dd + cc, __ATOMIC_RELAXED, __HIP_MEMORY_SCOPE_AGENT);
            vM += (double)__hip_atomic_load(ws + (1 * REP + r) * Dd + cc, __ATOMIC_RELAXED, __HIP_MEMORY_SCOPE_AGENT);
            vX += (double)__hip_atomic_load(ws + (2 * REP + r) * Dd + cc, __ATOMIC_RELAXED, __HIP_MEMORY_SCOPE_AGENT);
            v2 += (double)__hip_atomic_load(ws + (3 * REP + r) * Dd + cc, __ATOMIC_RELAXED, __HIP_MEMORY_SCOPE_AGENT);
        }
        dc += v2 * vI - 2.0 * vX * vM;
    }
    redd[t] = dc; __syncthreads();
    for (int s = 128; s > 0; s >>= 1) {
        if (t < s) redd[t] += redd[t + s];
        __syncthreads();
    }
    if (t == 0) {
        double* wd = (double*)((char*)ws + 524288);
        double P = 0.0, M2 = 0.0;
#pragma unroll
        for (int r = 0; r < REP; ++r) {
            P  += __hip_atomic_load(wd + r,       __ATOMIC_RELAXED, __HIP_MEMORY_SCOPE_AGENT);
            M2 += __hip_atomic_load(wd + REP + r, __ATOMIC_RELAXED, __HIP_MEMORY_SCOPE_AGENT);
        }
        const double sumD = redd[0] + (double)Nn * M2;
        out[0] = (float)((-0.5 / (double)Nn) * P
                       + (0.5 / ((double)Nn * (double)Nn)) * sumD);
    }
}

extern "C" void kernel_launch(void* const* d_in, const int* in_sizes, int n_in,
                              void* d_out, int out_size, void* d_ws, size_t ws_size,
                              hipStream_t stream) {
    const float* x    = (const float*)d_in[0];
    const float* p_mu = (const float*)d_in[1];
    const float* p_lv = (const float*)d_in[2];
    float* ws = (float*)d_ws;

    // zero: 512KB float accumulators + 128 doubles + counter
    hipMemsetAsync(d_ws, 0, 525316, stream);
    club_all<<<NBLK, 256, 0, stream>>>(x, p_mu, p_lv, ws, (float*)d_out);
}

// Round 10
// 105.010 us; speedup vs baseline: 1.4642x; 1.4642x over previous
//
#include <hip/hip_runtime.h>

// CLUB loss, algebraically collapsed (O(N*d), x read once):
//   out = -0.5/N * P + 0.5/N^2 * ( <Sx2,Sinv> - 2<Sx,Smuinv> + N*Smu2inv )
// Sinv[d]=sum_i e^{-lv}, Smuinv[d]=sum_i mu e^{-lv}, Sx[d]=sum_j x, Sx2[d]=sum_j x^2
// P = sum (x-mu)^2 e^{-lv},  Smu2inv = sum mu^2 e^{-lv}
//
// R10: R5's main kernel (best measured family: 1KB-contiguous wave loads,
// LDS x-transpose, 784 blocks) kept verbatim; tail slimmed: REP 64->16,
// fin reads 128KB (not 512KB) with 1024 thr, memset 131KB (not 525KB).

#define Dd   512
#define HWs  784
#define Nn   6272
#define LSx  260      // LDS x-tile stride: %4==0 (b128), %32==4 -> 2-way only (free)
#define REP  16

// ws floats: [(a*REP+rep)*512 + c], a: 0=Inv 1=Mu 2=Sx 3=Sx2 -> 128 KB
// doubles @byte 131072: P[16], M2[16]

__global__ __launch_bounds__(256) void club_main(
    const float* __restrict__ x, const float* __restrict__ p_mu,
    const float* __restrict__ p_lv, float* __restrict__ ws)
{
    __shared__ __align__(16) float smem[16 * LSx + 16];

    const int t   = threadIdx.x;
    const int bid = blockIdx.x;
    const int ct  = bid & 1;
    const int ht  = (bid >> 1) % 49;
    const int b   = bid / 98;
    const int c0  = ct * 256;
    const int hw0 = ht * 16;
    const int rep = bid & (REP - 1);

    // ---- issue ALL global loads first (12 dwordx4 in flight) ----
    const int dx = t >> 2;            // 0..63 (+64k)
    const int g  = t & 3;             // hw group within tile
    const float* xb = x + ((size_t)(b * Dd + c0 + dx) * HWs + hw0 + 4 * g);
    const float4 x0 = *(const float4*)(xb);
    const float4 x1 = *(const float4*)(xb +  64 * HWs);
    const float4 x2 = *(const float4*)(xb + 128 * HWs);
    const float4 x3 = *(const float4*)(xb + 192 * HWs);

    const int r0 = b * HWs + hw0;
    const size_t mbase = (size_t)(r0 + (t >> 6)) * Dd + c0 + 4 * (t & 63);
    const float* mp = p_mu + mbase;
    const float* lp = p_lv + mbase;
    const float4 m0 = *(const float4*)(mp);
    const float4 m1 = *(const float4*)(mp + 2048);
    const float4 m2 = *(const float4*)(mp + 4096);
    const float4 m3 = *(const float4*)(mp + 6144);
    const float4 l0 = *(const float4*)(lp);
    const float4 l1 = *(const float4*)(lp + 2048);
    const float4 l2 = *(const float4*)(lp + 4096);
    const float4 l3 = *(const float4*)(lp + 6144);

    // ---- transpose x into LDS: xs[hw_row][col] ----
    {
        const int rr = 4 * g;
#define XST(V, K) do {                                                \
        const int c = dx + 64 * (K);                                  \
        smem[(rr + 0) * LSx + c] = (V).x;                             \
        smem[(rr + 1) * LSx + c] = (V).y;                             \
        smem[(rr + 2) * LSx + c] = (V).z;                             \
        smem[(rr + 3) * LSx + c] = (V).w;                             \
    } while (0)
        XST(x0, 0); XST(x1, 1); XST(x2, 2); XST(x3, 3);
#undef XST
    }
    __syncthreads();

    // ---- main compute: thread owns cols 4*(t&63), rows (t>>6)+4k ----
    float4 aI = {0,0,0,0}, aM = {0,0,0,0}, sX = {0,0,0,0}, sX2 = {0,0,0,0};
    float aP = 0.f, aM2 = 0.f;
    const int cc = 4 * (t & 63);
    const int rb = t >> 6;

#define ACC1(XV, MU, LV, F) do {                                      \
        const float iev = __expf(-(LV).F);                            \
        const float dd  = (XV).F - (MU).F;                            \
        aP += dd * dd * iev;                                          \
        aI.F += iev;                                                  \
        const float mi = (MU).F * iev;                                \
        aM.F += mi; aM2 += (MU).F * mi;                               \
        sX.F += (XV).F; sX2.F += (XV).F * (XV).F;                     \
    } while (0)
#define ACCROW(K, MU, LV) do {                                        \
        const float4 xv = *(const float4*)&smem[(rb + 4 * (K)) * LSx + cc]; \
        ACC1(xv, MU, LV, x); ACC1(xv, MU, LV, y);                     \
        ACC1(xv, MU, LV, z); ACC1(xv, MU, LV, w);                     \
    } while (0)
    ACCROW(0, m0, l0); ACCROW(1, m1, l1); ACCROW(2, m2, l2); ACCROW(3, m3, l3);
#undef ACCROW
#undef ACC1

    // ---- per-column LDS reduces (t, t+64, t+128, t+192 share cols) ----
    float4* red4 = (float4*)smem;
    float4 rI, rM, rX, rX2;
#define COLRED(SRC, DST) do {                                         \
        __syncthreads();                                              \
        red4[t] = (SRC);                                              \
        __syncthreads();                                              \
        if (t < 128) { float4 o = red4[t + 128];                      \
            red4[t].x += o.x; red4[t].y += o.y;                       \
            red4[t].z += o.z; red4[t].w += o.w; }                     \
        __syncthreads();                                              \
        if (t < 64) { float4 a = red4[t], o = red4[t + 64];           \
            (DST).x = a.x + o.x; (DST).y = a.y + o.y;                 \
            (DST).z = a.z + o.z; (DST).w = a.w + o.w; }               \
    } while (0)
    COLRED(aI, rI); COLRED(aM, rM); COLRED(sX, rX); COLRED(sX2, rX2);
#undef COLRED

    // ---- scalar wave reduce, park in LDS (barriers BEFORE atomics) ----
#pragma unroll
    for (int off = 32; off > 0; off >>= 1) {
        aP  += __shfl_down(aP,  off);
        aM2 += __shfl_down(aM2, off);
    }
    __syncthreads();
    if ((t & 63) == 0) {
        smem[16 * LSx + (t >> 6)]     = aP;
        smem[16 * LSx + 8 + (t >> 6)] = aM2;
    }
    __syncthreads();

    // ---- fire-and-forget atomics to 16-way replicated accumulators ----
    if (t < 64) {
        const int c = c0 + 4 * t;
        float* wi = ws + (0 * REP + rep) * Dd + c;
        float* wm = ws + (1 * REP + rep) * Dd + c;
        float* wx = ws + (2 * REP + rep) * Dd + c;
        float* w2 = ws + (3 * REP + rep) * Dd + c;
        atomicAdd(wi + 0, rI.x); atomicAdd(wi + 1, rI.y);
        atomicAdd(wi + 2, rI.z); atomicAdd(wi + 3, rI.w);
        atomicAdd(wm + 0, rM.x); atomicAdd(wm + 1, rM.y);
        atomicAdd(wm + 2, rM.z); atomicAdd(wm + 3, rM.w);
        atomicAdd(wx + 0, rX.x); atomicAdd(wx + 1, rX.y);
        atomicAdd(wx + 2, rX.z); atomicAdd(wx + 3, rX.w);
        atomicAdd(w2 + 0, rX2.x); atomicAdd(w2 + 1, rX2.y);
        atomicAdd(w2 + 2, rX2.z); atomicAdd(w2 + 3, rX2.w);
    }
    if (t == 0) {
        double* wd = (double*)((char*)ws + 131072);
        atomicAdd(wd + rep, (double)(smem[16*LSx+0] + smem[16*LSx+1]
                                   + smem[16*LSx+2] + smem[16*LSx+3]));
        atomicAdd(wd + REP + rep, (double)(smem[16*LSx+8] + smem[16*LSx+9]
                                         + smem[16*LSx+10] + smem[16*LSx+11]));
    }
}

__global__ __launch_bounds__(1024) void club_fin(
    const float* __restrict__ ws, float* __restrict__ out)
{
    __shared__ float  L[8][Dd];     // [a*2 + half][c]
    __shared__ double red[1024];

    const int t = threadIdx.x;
    const int c = t & 511;
    const int h = t >> 9;           // 0/1: reps [0,8) / [8,16)

#pragma unroll
    for (int a = 0; a < 4; ++a) {
        float s = 0.f;
#pragma unroll
        for (int r = 8 * h; r < 8 * h + 8; ++r)
            s += ws[(a * REP + r) * Dd + c];
        L[a * 2 + h][c] = s;
    }
    __syncthreads();

    double dc = 0.0;
    if (h == 0) {
        const double sI  = (double)L[0][c] + L[1][c];
        const double sM  = (double)L[2][c] + L[3][c];
        const double sX  = (double)L[4][c] + L[5][c];
        const double sX2 = (double)L[6][c] + L[7][c];
        dc = sX2 * sI - 2.0 * sX * sM;
    }
    red[t] = dc; __syncthreads();
    for (int s = 512; s > 0; s >>= 1) {
        if (t < s) red[t] += red[t + s];
        __syncthreads();
    }

    if (t == 0) {
        const double* wd = (const double*)((const char*)ws + 131072);
        double P = 0.0, M2 = 0.0;
#pragma unroll
        for (int r = 0; r < REP; ++r) { P += wd[r]; M2 += wd[REP + r]; }
        const double sumD = red[0] + (double)Nn * M2;
        out[0] = (float)((-0.5 / (double)Nn) * P
                       + (0.5 / ((double)Nn * (double)Nn)) * sumD);
    }
}

extern "C" void kernel_launch(void* const* d_in, const int* in_sizes, int n_in,
                              void* d_out, int out_size, void* d_ws, size_t ws_size,
                              hipStream_t stream) {
    const float* x    = (const float*)d_in[0];
    const float* p_mu = (const float*)d_in[1];
    const float* p_lv = (const float*)d_in[2];
    float* ws = (float*)d_ws;

    // zero atomic accumulators: 128 KB floats + 32 doubles
    hipMemsetAsync(d_ws, 0, 131072 + 256, stream);

    club_main<<<784, 256, 0, stream>>>(x, p_mu, p_lv, ws);
    club_fin<<<1, 1024, 0, stream>>>(ws, (float*)d_out);
}